// Round 2
// baseline (353.399 us; speedup 1.0000x reference)
//
#include <hip/hip_runtime.h>

typedef __attribute__((ext_vector_type(4))) float  f32x4;
typedef __attribute__((ext_vector_type(4))) short  s16x4;
typedef __bf16 bf16x8 __attribute__((ext_vector_type(8)));

#define NBATCH 16
#define SEQ    4096
#define KIN    256
#define HY     64
#define HOUT   512
#define NROWS  (NBATCH*SEQ)   /* 65536 */
#define LC     32
#define NC     (SEQ/LC)       /* 128 */

static __device__ __forceinline__ short f2bf(float f) {
  unsigned u = __float_as_uint(f);
  u = u + 0x7FFF + ((u >> 16) & 1);          // RNE
  return (short)(u >> 16);
}
static __device__ __forceinline__ float bf2f(short h) {
  return __uint_as_float(((unsigned)(unsigned short)h) << 16);
}
static __device__ __forceinline__ f32x4 mfma16(bf16x8 a, bf16x8 b, f32x4 c) {
  return __builtin_amdgcn_mfma_f32_16x16x32_bf16(a, b, c, 0, 0, 0);
}
static __device__ __forceinline__ bf16x8 ldfrag(const short* p) {
  return *reinterpret_cast<const bf16x8*>(p);
}
static __device__ __forceinline__ float fsigmoid(float z) {
  return 1.f / (1.f + __expf(-z));
}

// ---------------- weight prep
__global__ void prep_w(const float* __restrict__ lin0W, const float* __restrict__ sig0W,
                       const float* __restrict__ fchW,  const float* __restrict__ fc2W,
                       short* __restrict__ W1h, short* __restrict__ W1l, short* __restrict__ W2h,
                       short* __restrict__ Fh,  short* __restrict__ F2h) {
  int i = blockIdx.x * 256 + threadIdx.x;
  if (i < 16384) {
    float v = lin0W[i]; short h = f2bf(v);
    W1h[i] = h; W1l[i] = f2bf(v - bf2f(h));
    W2h[i] = f2bf(sig0W[i]);
  } else if (i < 16384 + 32768) {
    int j = i - 16384;
    Fh[j] = f2bf(fchW[j]);
  } else if (i < 16384 + 32768 + 131072) {
    int j = i - 49152;
    F2h[j] = f2bf(fc2W[j]);
  }
}

// ---------------- g = relu( (x@lin0^T+b) * sigmoid(x@sig0^T+b) ), bf16 out
__global__ __launch_bounds__(256) void gemm_g(
    const float* __restrict__ x,
    const short* __restrict__ W1h, const short* __restrict__ W1l, const short* __restrict__ W2h,
    const float* __restrict__ lin0b, const float* __restrict__ sig0b,
    short* __restrict__ Gh) {
  __shared__ short Ah[64 * 256];
  __shared__ short Al[64 * 256];
  int tid = threadIdx.x;
  int row0 = blockIdx.x * 64;
  #pragma unroll
  for (int i = 0; i < 16; ++i) {
    int f4 = tid + i * 256;
    int r = f4 >> 6;
    int k = (f4 & 63) << 2;
    f32x4 v = *reinterpret_cast<const f32x4*>(x + (size_t)(row0 + r) * KIN + k);
    s16x4 hh, ll;
    #pragma unroll
    for (int j = 0; j < 4; ++j) {
      short hb = f2bf(v[j]);
      hh[j] = hb;
      ll[j] = f2bf(v[j] - bf2f(hb));
    }
    int sidx = (r * 256 + k) ^ ((r & 7) << 3);
    *reinterpret_cast<s16x4*>(&Ah[sidx]) = hh;
    *reinterpret_cast<s16x4*>(&Al[sidx]) = ll;
  }
  __syncthreads();
  int w = tid >> 6, l = tid & 63;
  int lr = l & 15, lg = l >> 4;
  int c = w * 16 + lr;
  f32x4 acc1[4], acc2[4];
  #pragma unroll
  for (int rt = 0; rt < 4; ++rt) { acc1[rt] = (f32x4)0.f; acc2[rt] = (f32x4)0.f; }
  #pragma unroll
  for (int ks = 0; ks < 8; ++ks) {
    int kk = ks * 32 + lg * 8;
    bf16x8 b2 = ldfrag(W2h + c * 256 + kk);
    #pragma unroll
    for (int rt = 0; rt < 4; ++rt) {
      int r = rt * 16 + lr;
      bf16x8 a = ldfrag(&Ah[(r * 256 + kk) ^ ((r & 7) << 3)]);
      acc2[rt] = mfma16(a, b2, acc2[rt]);
    }
  }
  #pragma unroll
  for (int ks = 0; ks < 8; ++ks) {
    int kk = ks * 32 + lg * 8;
    bf16x8 b1h = ldfrag(W1h + c * 256 + kk);
    bf16x8 b1l = ldfrag(W1l + c * 256 + kk);
    #pragma unroll
    for (int rt = 0; rt < 4; ++rt) {
      int r = rt * 16 + lr;
      int si = (r * 256 + kk) ^ ((r & 7) << 3);
      bf16x8 ah = ldfrag(&Ah[si]);
      bf16x8 al = ldfrag(&Al[si]);
      acc1[rt] = mfma16(ah, b1h, acc1[rt]);
      acc1[rt] = mfma16(ah, b1l, acc1[rt]);
      acc1[rt] = mfma16(al, b1h, acc1[rt]);
    }
  }
  float bl = lin0b[c], bs = sig0b[c];
  #pragma unroll
  for (int rt = 0; rt < 4; ++rt) {
    #pragma unroll
    for (int j = 0; j < 4; ++j) {
      int row = row0 + rt * 16 + lg * 4 + j;
      float y1 = acc1[rt][j] + bl;
      float y2 = acc2[rt][j] + bs;
      float g = y1 * fsigmoid(y2);
      g = g > 0.f ? g : 0.f;
      Gh[(size_t)row * HY + c] = f2bf(g);
    }
  }
}

// ---------------- b = (g@fch^T + b) * sigmoid(x@fc2^T + b), fp32 -> d_out
// grid: rowTile (1024) x colHalf (2). block: 64 rows x 256 cols, 4 waves (64 cols each).
__global__ __launch_bounds__(256, 4) void gemm_b(
    const float* __restrict__ x,
    const short* __restrict__ Gh,
    const short* __restrict__ F2h, const short* __restrict__ Fh,
    const float* __restrict__ fchb, const float* __restrict__ fc2b,
    float* __restrict__ bout) {
  __shared__ short Ax[64 * 256];
  __shared__ short SgH[64 * 64];
  int tid = threadIdx.x;
  int rowTile = blockIdx.x >> 1;
  int colHalf = blockIdx.x & 1;
  int row0 = rowTile * 64;
  int col0 = colHalf * 256;
  #pragma unroll
  for (int i = 0; i < 16; ++i) {
    int f4 = tid + i * 256;
    int r = f4 >> 6, k = (f4 & 63) << 2;
    f32x4 v = *reinterpret_cast<const f32x4*>(x + (size_t)(row0 + r) * KIN + k);
    s16x4 hh;
    #pragma unroll
    for (int j = 0; j < 4; ++j) hh[j] = f2bf(v[j]);
    *reinterpret_cast<s16x4*>(&Ax[(r * 256 + k) ^ ((r & 7) << 3)]) = hh;
  }
  #pragma unroll
  for (int i = 0; i < 4; ++i) {
    int s4 = tid + i * 256;
    int r = s4 >> 4, k = (s4 & 15) << 2;
    s16x4 vh = *reinterpret_cast<const s16x4*>(Gh + (size_t)(row0 + r) * HY + k);
    *reinterpret_cast<s16x4*>(&SgH[(r * 64 + k) ^ ((r & 7) << 3)]) = vh;
  }
  __syncthreads();
  int w = tid >> 6, l = tid & 63;
  int lr = l & 15, lg = l >> 4;
  for (int ct = 0; ct < 4; ++ct) {
    int c = col0 + w * 64 + ct * 16 + lr;
    f32x4 a2[4], af[4];
    #pragma unroll
    for (int rt = 0; rt < 4; ++rt) { a2[rt] = (f32x4)0.f; af[rt] = (f32x4)0.f; }
    #pragma unroll
    for (int ks = 0; ks < 8; ++ks) {          // fc2 (plain bf16, feeds sigmoid)
      int kk = ks * 32 + lg * 8;
      bf16x8 b = ldfrag(F2h + (size_t)c * 256 + kk);
      #pragma unroll
      for (int rt = 0; rt < 4; ++rt) {
        int r = rt * 16 + lr;
        bf16x8 a = ldfrag(&Ax[(r * 256 + kk) ^ ((r & 7) << 3)]);
        a2[rt] = mfma16(a, b, a2[rt]);
      }
    }
    #pragma unroll
    for (int ks = 0; ks < 2; ++ks) {          // fch (plain bf16)
      int kk = ks * 32 + lg * 8;
      bf16x8 bh = ldfrag(Fh + (size_t)c * 64 + kk);
      #pragma unroll
      for (int rt = 0; rt < 4; ++rt) {
        int r = rt * 16 + lr;
        bf16x8 gh = ldfrag(&SgH[(r * 64 + kk) ^ ((r & 7) << 3)]);
        af[rt] = mfma16(gh, bh, af[rt]);
      }
    }
    float bc = fchb[c], b2c = fc2b[c];
    #pragma unroll
    for (int rt = 0; rt < 4; ++rt) {
      #pragma unroll
      for (int j = 0; j < 4; ++j) {
        int row = row0 + rt * 16 + lg * 4 + j;
        float alpha = fsigmoid(a2[rt][j] + b2c);
        bout[(size_t)row * HOUT + c] = (af[rt][j] + bc) * alpha;
      }
    }
  }
}

// ---------------- scan pass A: per-chunk max-plus operator (C,S). 1 wave/wg, 8 ch/lane.
__global__ __launch_bounds__(64) void scan_passA(const float* __restrict__ bm,
                                                 float* __restrict__ Cc, float* __restrict__ Sc) {
  int bc = blockIdx.x;
  int batch = bc >> 7, chunk = bc & (NC - 1);
  int l = threadIdx.x;
  const float* bp = bm + ((size_t)batch * SEQ + chunk * LC) * HOUT + l * 8;
  f32x4 v0 = *reinterpret_cast<const f32x4*>(bp);
  f32x4 v1 = *reinterpret_cast<const f32x4*>(bp + 4);
  float C[8], S[8];
  #pragma unroll
  for (int i = 0; i < 4; ++i) { S[i] = v0[i]; S[4 + i] = v1[i]; C[i] = 0.f; C[4 + i] = 0.f; }
  for (int t = 1; t < LC; ++t) {
    const float* bt = bp + (size_t)t * HOUT;
    v0 = *reinterpret_cast<const f32x4*>(bt);
    v1 = *reinterpret_cast<const f32x4*>(bt + 4);
    float bb[8];
    #pragma unroll
    for (int i = 0; i < 4; ++i) { bb[i] = v0[i]; bb[4 + i] = v1[i]; }
    float pC = __shfl(C[7], (l + 63) & 63);
    float pS = __shfl(S[7], (l + 63) & 63);
    #pragma unroll
    for (int i = 7; i >= 1; --i) { C[i] = fmaxf(0.f, bb[i] + C[i - 1]); S[i] = bb[i] + S[i - 1]; }
    C[0] = fmaxf(0.f, bb[0] + pC);
    S[0] = bb[0] + pS;
  }
  float* cp = Cc + (size_t)bc * HOUT + l * 8;
  float* sp = Sc + (size_t)bc * HOUT + l * 8;
  #pragma unroll
  for (int i = 0; i < 8; ++i) { cp[i] = C[i]; sp[i] = S[i]; }
}

// ---------------- combine: sequential over chunks per batch; emits h_in per chunk + last.
__global__ __launch_bounds__(64) void scan_combine(const float* __restrict__ hidden,
                                                   const float* __restrict__ Cc, const float* __restrict__ Sc,
                                                   float* __restrict__ hIn, float* __restrict__ lastOut) {
  int batch = blockIdx.x;
  int l = threadIdx.x;
  float h[8];
  const float* hp = hidden + batch * HOUT + l * 8;
  #pragma unroll
  for (int i = 0; i < 8; ++i) h[i] = hp[i];
  size_t base0 = ((size_t)batch * NC) * HOUT + l * 8;
  f32x4 c0 = *reinterpret_cast<const f32x4*>(Cc + base0);
  f32x4 c1 = *reinterpret_cast<const f32x4*>(Cc + base0 + 4);
  f32x4 s0 = *reinterpret_cast<const f32x4*>(Sc + base0);
  f32x4 s1 = *reinterpret_cast<const f32x4*>(Sc + base0 + 4);
  for (int c = 0; c < NC; ++c) {
    size_t base = base0 + (size_t)c * HOUT;
    f32x4 nc0, nc1, ns0, ns1;
    if (c + 1 < NC) {
      size_t nb = base + HOUT;
      nc0 = *reinterpret_cast<const f32x4*>(Cc + nb);
      nc1 = *reinterpret_cast<const f32x4*>(Cc + nb + 4);
      ns0 = *reinterpret_cast<const f32x4*>(Sc + nb);
      ns1 = *reinterpret_cast<const f32x4*>(Sc + nb + 4);
    }
    #pragma unroll
    for (int i = 0; i < 8; ++i) hIn[base + i] = h[i];
    float hs[8];
    #pragma unroll
    for (int i = 0; i < 8; ++i) hs[i] = __shfl(h[i], (l + 64 - (LC / 8)) & 63);
    #pragma unroll
    for (int i = 0; i < 4; ++i) {
      h[i]     = fmaxf(c0[i], s0[i] + hs[i]);
      h[4 + i] = fmaxf(c1[i], s1[i] + hs[4 + i]);
    }
    c0 = nc0; c1 = nc1; s0 = ns0; s1 = ns1;
  }
  float* lp = lastOut + batch * HOUT + l * 8;
  #pragma unroll
  for (int i = 0; i < 8; ++i) lp[i] = h[i];
}

// ---------------- pass B: replay recurrence within chunk, overwrite b with h in place.
__global__ __launch_bounds__(64) void scan_passB(float* __restrict__ bm, const float* __restrict__ hIn) {
  int bc = blockIdx.x;
  int batch = bc >> 7, chunk = bc & (NC - 1);
  int l = threadIdx.x;
  const float* hp = hIn + (size_t)bc * HOUT + l * 8;
  float h[8];
  #pragma unroll
  for (int i = 0; i < 8; ++i) h[i] = hp[i];
  float* bp = bm + ((size_t)batch * SEQ + chunk * LC) * HOUT + l * 8;
  for (int t = 0; t < LC; ++t) {
    float* bt = bp + (size_t)t * HOUT;
    f32x4 v0 = *reinterpret_cast<const f32x4*>(bt);
    f32x4 v1 = *reinterpret_cast<const f32x4*>(bt + 4);
    float bb[8];
    #pragma unroll
    for (int i = 0; i < 4; ++i) { bb[i] = v0[i]; bb[4 + i] = v1[i]; }
    float ph = __shfl(h[7], (l + 63) & 63);
    #pragma unroll
    for (int i = 7; i >= 1; --i) h[i] = fmaxf(0.f, bb[i] + h[i - 1]);
    h[0] = fmaxf(0.f, bb[0] + ph);
    f32x4 o0, o1;
    #pragma unroll
    for (int i = 0; i < 4; ++i) { o0[i] = h[i]; o1[i] = h[4 + i]; }
    *reinterpret_cast<f32x4*>(bt) = o0;
    *reinterpret_cast<f32x4*>(bt + 4) = o1;
  }
}

extern "C" void kernel_launch(void* const* d_in, const int* in_sizes, int n_in,
                              void* d_out, int out_size, void* d_ws, size_t ws_size,
                              hipStream_t stream) {
  (void)in_sizes; (void)n_in; (void)out_size; (void)ws_size;
  const float* x      = (const float*)d_in[0];
  const float* hidden = (const float*)d_in[1];
  const float* lin0W  = (const float*)d_in[2];
  const float* lin0b  = (const float*)d_in[3];
  const float* sig0W  = (const float*)d_in[4];
  const float* sig0b  = (const float*)d_in[5];
  const float* fchW   = (const float*)d_in[6];
  const float* fchb   = (const float*)d_in[7];
  const float* fc2W   = (const float*)d_in[8];
  const float* fc2b   = (const float*)d_in[9];
  float* outO  = (float*)d_out;
  float* lastO = outO + (size_t)NROWS * HOUT;

  char* wsb = (char*)d_ws;
  size_t off = 0;
  auto alloc = [&](size_t bytes) { char* p = wsb + off; off += (bytes + 255) & ~(size_t)255; return p; };
  float* Cc  = (float*)alloc((size_t)NBATCH * NC * HOUT * 4);
  float* Sc  = (float*)alloc((size_t)NBATCH * NC * HOUT * 4);
  float* hIn = (float*)alloc((size_t)NBATCH * NC * HOUT * 4);
  short* W1h = (short*)alloc(HY * KIN * 2);
  short* W1l = (short*)alloc(HY * KIN * 2);
  short* W2h = (short*)alloc(HY * KIN * 2);
  short* Fh  = (short*)alloc(HOUT * HY * 2);
  short* F2h = (short*)alloc(HOUT * KIN * 2);
  short* Gh  = (short*)alloc((size_t)NROWS * HY * 2);

  prep_w<<<704, 256, 0, stream>>>(lin0W, sig0W, fchW, fc2W, W1h, W1l, W2h, Fh, F2h);
  gemm_g<<<NROWS / 64, 256, 0, stream>>>(x, W1h, W1l, W2h, lin0b, sig0b, Gh);
  gemm_b<<<NROWS / 32, 256, 0, stream>>>(x, Gh, F2h, Fh, fchb, fc2b, outO);
  scan_passA<<<NBATCH * NC, 64, 0, stream>>>(outO, Cc, Sc);
  scan_combine<<<NBATCH, 64, 0, stream>>>(hidden, Cc, Sc, hIn, lastO);
  scan_passB<<<NBATCH * NC, 64, 0, stream>>>(outO, hIn);
}

// Round 3
// 262.275 us; speedup vs baseline: 1.3474x; 1.3474x over previous
//
#include <hip/hip_runtime.h>

typedef __attribute__((ext_vector_type(4))) float  f32x4;
typedef __attribute__((ext_vector_type(4))) short  s16x4;
typedef __bf16 bf16x8 __attribute__((ext_vector_type(8)));

#define NBATCH 16
#define SEQ    4096
#define KIN    256
#define HY     64
#define HOUT   512
#define NROWS  (NBATCH*SEQ)   /* 65536 */
#define LC     32
#define NC     (SEQ/LC)       /* 128 */

static __device__ __forceinline__ short f2bf(float f) {
  unsigned u = __float_as_uint(f);
  u = u + 0x7FFF + ((u >> 16) & 1);          // RNE
  return (short)(u >> 16);
}
static __device__ __forceinline__ float bf2f(short h) {
  return __uint_as_float(((unsigned)(unsigned short)h) << 16);
}
static __device__ __forceinline__ f32x4 mfma16(bf16x8 a, bf16x8 b, f32x4 c) {
  return __builtin_amdgcn_mfma_f32_16x16x32_bf16(a, b, c, 0, 0, 0);
}
static __device__ __forceinline__ bf16x8 ldfrag(const short* p) {
  return *reinterpret_cast<const bf16x8*>(p);
}
static __device__ __forceinline__ float fsigmoid(float z) {
  return 1.f / (1.f + __expf(-z));
}

// ---------------- weight prep
__global__ void prep_w(const float* __restrict__ lin0W, const float* __restrict__ sig0W,
                       const float* __restrict__ fchW,  const float* __restrict__ fc2W,
                       short* __restrict__ W1h, short* __restrict__ W1l, short* __restrict__ W2h,
                       short* __restrict__ Fh,  short* __restrict__ F2h) {
  int i = blockIdx.x * 256 + threadIdx.x;
  if (i < 16384) {
    float v = lin0W[i]; short h = f2bf(v);
    W1h[i] = h; W1l[i] = f2bf(v - bf2f(h));
    W2h[i] = f2bf(sig0W[i]);
  } else if (i < 16384 + 32768) {
    int j = i - 16384;
    Fh[j] = f2bf(fchW[j]);
  } else if (i < 16384 + 32768 + 131072) {
    int j = i - 49152;
    F2h[j] = f2bf(fc2W[j]);
  }
}

// ---------------- g = relu( (x@lin0^T+b) * sigmoid(x@sig0^T+b) ), bf16 out
__global__ __launch_bounds__(256) void gemm_g(
    const float* __restrict__ x,
    const short* __restrict__ W1h, const short* __restrict__ W1l, const short* __restrict__ W2h,
    const float* __restrict__ lin0b, const float* __restrict__ sig0b,
    short* __restrict__ Gh) {
  __shared__ short Ah[64 * 256];
  __shared__ short Al[64 * 256];
  int tid = threadIdx.x;
  int row0 = blockIdx.x * 64;
  #pragma unroll
  for (int i = 0; i < 16; ++i) {
    int f4 = tid + i * 256;
    int r = f4 >> 6;
    int k = (f4 & 63) << 2;
    f32x4 v = *reinterpret_cast<const f32x4*>(x + (size_t)(row0 + r) * KIN + k);
    s16x4 hh, ll;
    #pragma unroll
    for (int j = 0; j < 4; ++j) {
      short hb = f2bf(v[j]);
      hh[j] = hb;
      ll[j] = f2bf(v[j] - bf2f(hb));
    }
    int sidx = (r * 256 + k) ^ ((r & 7) << 3);
    *reinterpret_cast<s16x4*>(&Ah[sidx]) = hh;
    *reinterpret_cast<s16x4*>(&Al[sidx]) = ll;
  }
  __syncthreads();
  int w = tid >> 6, l = tid & 63;
  int lr = l & 15, lg = l >> 4;
  int c = w * 16 + lr;
  f32x4 acc1[4], acc2[4];
  #pragma unroll
  for (int rt = 0; rt < 4; ++rt) { acc1[rt] = (f32x4)0.f; acc2[rt] = (f32x4)0.f; }
  #pragma unroll
  for (int ks = 0; ks < 8; ++ks) {
    int kk = ks * 32 + lg * 8;
    bf16x8 b2 = ldfrag(W2h + c * 256 + kk);
    #pragma unroll
    for (int rt = 0; rt < 4; ++rt) {
      int r = rt * 16 + lr;
      bf16x8 a = ldfrag(&Ah[(r * 256 + kk) ^ ((r & 7) << 3)]);
      acc2[rt] = mfma16(a, b2, acc2[rt]);
    }
  }
  #pragma unroll
  for (int ks = 0; ks < 8; ++ks) {
    int kk = ks * 32 + lg * 8;
    bf16x8 b1h = ldfrag(W1h + c * 256 + kk);
    bf16x8 b1l = ldfrag(W1l + c * 256 + kk);
    #pragma unroll
    for (int rt = 0; rt < 4; ++rt) {
      int r = rt * 16 + lr;
      int si = (r * 256 + kk) ^ ((r & 7) << 3);
      bf16x8 ah = ldfrag(&Ah[si]);
      bf16x8 al = ldfrag(&Al[si]);
      acc1[rt] = mfma16(ah, b1h, acc1[rt]);
      acc1[rt] = mfma16(ah, b1l, acc1[rt]);
      acc1[rt] = mfma16(al, b1h, acc1[rt]);
    }
  }
  float bl = lin0b[c], bs = sig0b[c];
  #pragma unroll
  for (int rt = 0; rt < 4; ++rt) {
    #pragma unroll
    for (int j = 0; j < 4; ++j) {
      int row = row0 + rt * 16 + lg * 4 + j;
      float y1 = acc1[rt][j] + bl;
      float y2 = acc2[rt][j] + bs;
      float g = y1 * fsigmoid(y2);
      g = g > 0.f ? g : 0.f;
      Gh[(size_t)row * HY + c] = f2bf(g);
    }
  }
}

// ---------------- b = (g@fch^T + b) * sigmoid(x@fc2^T + b), fp32 -> d_out
// 1024 blocks, 64 rows x 512 cols each. wave w owns cols [128w,128w+128).
// 2-stream ct loop: (ct2, ct2+4) concurrently -> 2 indep MFMA chains, A-frag reuse x2.
__global__ __launch_bounds__(256, 4) void gemm_b(
    const float* __restrict__ x,
    const short* __restrict__ Gh,
    const short* __restrict__ F2h, const short* __restrict__ Fh,
    const float* __restrict__ fchb, const float* __restrict__ fc2b,
    float* __restrict__ bout) {
  __shared__ short Ax[64 * 256];
  __shared__ short SgH[64 * 64];
  int tid = threadIdx.x;
  int row0 = blockIdx.x * 64;
  #pragma unroll
  for (int i = 0; i < 16; ++i) {
    int f4 = tid + i * 256;
    int r = f4 >> 6, k = (f4 & 63) << 2;
    f32x4 v = *reinterpret_cast<const f32x4*>(x + (size_t)(row0 + r) * KIN + k);
    s16x4 hh;
    #pragma unroll
    for (int j = 0; j < 4; ++j) hh[j] = f2bf(v[j]);
    *reinterpret_cast<s16x4*>(&Ax[(r * 256 + k) ^ ((r & 7) << 3)]) = hh;
  }
  #pragma unroll
  for (int i = 0; i < 4; ++i) {
    int s4 = tid + i * 256;
    int r = s4 >> 4, k = (s4 & 15) << 2;
    s16x4 vh = *reinterpret_cast<const s16x4*>(Gh + (size_t)(row0 + r) * HY + k);
    *reinterpret_cast<s16x4*>(&SgH[(r * 64 + k) ^ ((r & 7) << 3)]) = vh;
  }
  __syncthreads();
  int w = tid >> 6, l = tid & 63;
  int lr = l & 15, lg = l >> 4;
  #pragma unroll
  for (int ct2 = 0; ct2 < 4; ++ct2) {
    int c0 = w * 128 + ct2 * 16 + lr;
    int c1 = c0 + 64;
    f32x4 a2[2][4], af[2][4];
    #pragma unroll
    for (int s = 0; s < 2; ++s)
      #pragma unroll
      for (int rt = 0; rt < 4; ++rt) { a2[s][rt] = (f32x4)0.f; af[s][rt] = (f32x4)0.f; }
    #pragma unroll
    for (int ks = 0; ks < 8; ++ks) {          // fc2 (plain bf16, feeds sigmoid)
      int kk = ks * 32 + lg * 8;
      bf16x8 b0 = ldfrag(F2h + (size_t)c0 * 256 + kk);
      bf16x8 b1 = ldfrag(F2h + (size_t)c1 * 256 + kk);
      #pragma unroll
      for (int rt = 0; rt < 4; ++rt) {
        int r = rt * 16 + lr;
        bf16x8 a = ldfrag(&Ax[(r * 256 + kk) ^ ((r & 7) << 3)]);
        a2[0][rt] = mfma16(a, b0, a2[0][rt]);
        a2[1][rt] = mfma16(a, b1, a2[1][rt]);
      }
    }
    #pragma unroll
    for (int ks = 0; ks < 2; ++ks) {          // fch (plain bf16)
      int kk = ks * 32 + lg * 8;
      bf16x8 b0 = ldfrag(Fh + (size_t)c0 * 64 + kk);
      bf16x8 b1 = ldfrag(Fh + (size_t)c1 * 64 + kk);
      #pragma unroll
      for (int rt = 0; rt < 4; ++rt) {
        int r = rt * 16 + lr;
        bf16x8 gh = ldfrag(&SgH[(r * 64 + kk) ^ ((r & 7) << 3)]);
        af[0][rt] = mfma16(gh, b0, af[0][rt]);
        af[1][rt] = mfma16(gh, b1, af[1][rt]);
      }
    }
    #pragma unroll
    for (int s = 0; s < 2; ++s) {
      int c = s ? c1 : c0;
      float bc = fchb[c], b2c = fc2b[c];
      #pragma unroll
      for (int rt = 0; rt < 4; ++rt) {
        #pragma unroll
        for (int j = 0; j < 4; ++j) {
          int row = row0 + rt * 16 + lg * 4 + j;
          float alpha = fsigmoid(a2[s][rt][j] + b2c);
          bout[(size_t)row * HOUT + c] = (af[s][rt][j] + bc) * alpha;
        }
      }
    }
  }
}

// ---------------- scan pass A: per-chunk max-plus operator (C,S). 1 wave/wg, 8 ch/lane.
__global__ __launch_bounds__(64) void scan_passA(const float* __restrict__ bm,
                                                 float* __restrict__ Cc, float* __restrict__ Sc) {
  int bc = blockIdx.x;
  int batch = bc >> 7, chunk = bc & (NC - 1);
  int l = threadIdx.x;
  const float* bp = bm + ((size_t)batch * SEQ + chunk * LC) * HOUT + l * 8;
  f32x4 v0 = *reinterpret_cast<const f32x4*>(bp);
  f32x4 v1 = *reinterpret_cast<const f32x4*>(bp + 4);
  float C[8], S[8];
  #pragma unroll
  for (int i = 0; i < 4; ++i) { S[i] = v0[i]; S[4 + i] = v1[i]; C[i] = 0.f; C[4 + i] = 0.f; }
  for (int t = 1; t < LC; ++t) {
    const float* bt = bp + (size_t)t * HOUT;
    v0 = *reinterpret_cast<const f32x4*>(bt);
    v1 = *reinterpret_cast<const f32x4*>(bt + 4);
    float bb[8];
    #pragma unroll
    for (int i = 0; i < 4; ++i) { bb[i] = v0[i]; bb[4 + i] = v1[i]; }
    float pC = __shfl(C[7], (l + 63) & 63);
    float pS = __shfl(S[7], (l + 63) & 63);
    #pragma unroll
    for (int i = 7; i >= 1; --i) { C[i] = fmaxf(0.f, bb[i] + C[i - 1]); S[i] = bb[i] + S[i - 1]; }
    C[0] = fmaxf(0.f, bb[0] + pC);
    S[0] = bb[0] + pS;
  }
  float* cp = Cc + (size_t)bc * HOUT + l * 8;
  float* sp = Sc + (size_t)bc * HOUT + l * 8;
  #pragma unroll
  for (int i = 0; i < 8; ++i) { cp[i] = C[i]; sp[i] = S[i]; }
}

// ---------------- combine: sequential over chunks per batch; emits h_in per chunk + last.
__global__ __launch_bounds__(64) void scan_combine(const float* __restrict__ hidden,
                                                   const float* __restrict__ Cc, const float* __restrict__ Sc,
                                                   float* __restrict__ hIn, float* __restrict__ lastOut) {
  int batch = blockIdx.x;
  int l = threadIdx.x;
  float h[8];
  const float* hp = hidden + batch * HOUT + l * 8;
  #pragma unroll
  for (int i = 0; i < 8; ++i) h[i] = hp[i];
  size_t base0 = ((size_t)batch * NC) * HOUT + l * 8;
  f32x4 c0 = *reinterpret_cast<const f32x4*>(Cc + base0);
  f32x4 c1 = *reinterpret_cast<const f32x4*>(Cc + base0 + 4);
  f32x4 s0 = *reinterpret_cast<const f32x4*>(Sc + base0);
  f32x4 s1 = *reinterpret_cast<const f32x4*>(Sc + base0 + 4);
  for (int c = 0; c < NC; ++c) {
    size_t base = base0 + (size_t)c * HOUT;
    f32x4 nc0, nc1, ns0, ns1;
    if (c + 1 < NC) {
      size_t nb = base + HOUT;
      nc0 = *reinterpret_cast<const f32x4*>(Cc + nb);
      nc1 = *reinterpret_cast<const f32x4*>(Cc + nb + 4);
      ns0 = *reinterpret_cast<const f32x4*>(Sc + nb);
      ns1 = *reinterpret_cast<const f32x4*>(Sc + nb + 4);
    }
    #pragma unroll
    for (int i = 0; i < 8; ++i) hIn[base + i] = h[i];
    float hs[8];
    #pragma unroll
    for (int i = 0; i < 8; ++i) hs[i] = __shfl(h[i], (l + 64 - (LC / 8)) & 63);
    #pragma unroll
    for (int i = 0; i < 4; ++i) {
      h[i]     = fmaxf(c0[i], s0[i] + hs[i]);
      h[4 + i] = fmaxf(c1[i], s1[i] + hs[4 + i]);
    }
    c0 = nc0; c1 = nc1; s0 = ns0; s1 = ns1;
  }
  float* lp = lastOut + batch * HOUT + l * 8;
  #pragma unroll
  for (int i = 0; i < 8; ++i) lp[i] = h[i];
}

// ---------------- pass B: replay recurrence within chunk, overwrite b with h in place.
__global__ __launch_bounds__(64) void scan_passB(float* __restrict__ bm, const float* __restrict__ hIn) {
  int bc = blockIdx.x;
  int batch = bc >> 7, chunk = bc & (NC - 1);
  int l = threadIdx.x;
  const float* hp = hIn + (size_t)bc * HOUT + l * 8;
  float h[8];
  #pragma unroll
  for (int i = 0; i < 8; ++i) h[i] = hp[i];
  float* bp = bm + ((size_t)batch * SEQ + chunk * LC) * HOUT + l * 8;
  for (int t = 0; t < LC; ++t) {
    float* bt = bp + (size_t)t * HOUT;
    f32x4 v0 = *reinterpret_cast<const f32x4*>(bt);
    f32x4 v1 = *reinterpret_cast<const f32x4*>(bt + 4);
    float bb[8];
    #pragma unroll
    for (int i = 0; i < 4; ++i) { bb[i] = v0[i]; bb[4 + i] = v1[i]; }
    float ph = __shfl(h[7], (l + 63) & 63);
    #pragma unroll
    for (int i = 7; i >= 1; --i) h[i] = fmaxf(0.f, bb[i] + h[i - 1]);
    h[0] = fmaxf(0.f, bb[0] + ph);
    f32x4 o0, o1;
    #pragma unroll
    for (int i = 0; i < 4; ++i) { o0[i] = h[i]; o1[i] = h[4 + i]; }
    *reinterpret_cast<f32x4*>(bt) = o0;
    *reinterpret_cast<f32x4*>(bt + 4) = o1;
  }
}

extern "C" void kernel_launch(void* const* d_in, const int* in_sizes, int n_in,
                              void* d_out, int out_size, void* d_ws, size_t ws_size,
                              hipStream_t stream) {
  (void)in_sizes; (void)n_in; (void)out_size; (void)ws_size;
  const float* x      = (const float*)d_in[0];
  const float* hidden = (const float*)d_in[1];
  const float* lin0W  = (const float*)d_in[2];
  const float* lin0b  = (const float*)d_in[3];
  const float* sig0W  = (const float*)d_in[4];
  const float* sig0b  = (const float*)d_in[5];
  const float* fchW   = (const float*)d_in[6];
  const float* fchb   = (const float*)d_in[7];
  const float* fc2W   = (const float*)d_in[8];
  const float* fc2b   = (const float*)d_in[9];
  float* outO  = (float*)d_out;
  float* lastO = outO + (size_t)NROWS * HOUT;

  char* wsb = (char*)d_ws;
  size_t off = 0;
  auto alloc = [&](size_t bytes) { char* p = wsb + off; off += (bytes + 255) & ~(size_t)255; return p; };
  float* Cc  = (float*)alloc((size_t)NBATCH * NC * HOUT * 4);
  float* Sc  = (float*)alloc((size_t)NBATCH * NC * HOUT * 4);
  float* hIn = (float*)alloc((size_t)NBATCH * NC * HOUT * 4);
  short* W1h = (short*)alloc(HY * KIN * 2);
  short* W1l = (short*)alloc(HY * KIN * 2);
  short* W2h = (short*)alloc(HY * KIN * 2);
  short* Fh  = (short*)alloc(HOUT * HY * 2);
  short* F2h = (short*)alloc(HOUT * KIN * 2);
  short* Gh  = (short*)alloc((size_t)NROWS * HY * 2);

  prep_w<<<704, 256, 0, stream>>>(lin0W, sig0W, fchW, fc2W, W1h, W1l, W2h, Fh, F2h);
  gemm_g<<<NROWS / 64, 256, 0, stream>>>(x, W1h, W1l, W2h, lin0b, sig0b, Gh);
  gemm_b<<<NROWS / 64, 256, 0, stream>>>(x, Gh, F2h, Fh, fchb, fc2b, outO);
  scan_passA<<<NBATCH * NC, 64, 0, stream>>>(outO, Cc, Sc);
  scan_combine<<<NBATCH, 64, 0, stream>>>(hidden, Cc, Sc, hIn, lastO);
  scan_passB<<<NBATCH * NC, 64, 0, stream>>>(outO, hIn);
}

// Round 4
// 198.834 us; speedup vs baseline: 1.7774x; 1.3191x over previous
//
#include <hip/hip_runtime.h>

typedef __attribute__((ext_vector_type(4))) float  f32x4;
typedef __attribute__((ext_vector_type(4))) short  s16x4;
typedef __bf16 bf16x8 __attribute__((ext_vector_type(8)));

#define NBATCH 16
#define SEQ    4096
#define KIN    256
#define HY     64
#define HOUT   512
#define NROWS  (NBATCH*SEQ)   /* 65536 */
#define LC     32
#define NC     (SEQ/LC)       /* 128 */

#define GP(x) ((const __attribute__((address_space(1))) void*)(x))
#define LP(x) ((__attribute__((address_space(3))) void*)(x))

static __device__ __forceinline__ short f2bf(float f) {
  unsigned u = __float_as_uint(f);
  u = u + 0x7FFF + ((u >> 16) & 1);          // RNE
  return (short)(u >> 16);
}
static __device__ __forceinline__ float bf2f(short h) {
  return __uint_as_float(((unsigned)(unsigned short)h) << 16);
}
static __device__ __forceinline__ f32x4 mfma16(bf16x8 a, bf16x8 b, f32x4 c) {
  return __builtin_amdgcn_mfma_f32_16x16x32_bf16(a, b, c, 0, 0, 0);
}
static __device__ __forceinline__ bf16x8 ldfrag(const short* p) {
  return *reinterpret_cast<const bf16x8*>(p);
}
static __device__ __forceinline__ float fsigmoid(float z) {
  return 1.f / (1.f + __expf(-z));
}

// ---------------- weight prep
__global__ void prep_w(const float* __restrict__ lin0W, const float* __restrict__ sig0W,
                       const float* __restrict__ fchW,  const float* __restrict__ fc2W,
                       short* __restrict__ W1h, short* __restrict__ W1l, short* __restrict__ W2h,
                       short* __restrict__ Fh,  short* __restrict__ F2h) {
  int i = blockIdx.x * 256 + threadIdx.x;
  if (i < 16384) {
    float v = lin0W[i]; short h = f2bf(v);
    W1h[i] = h; W1l[i] = f2bf(v - bf2f(h));
    W2h[i] = f2bf(sig0W[i]);
  } else if (i < 16384 + 32768) {
    int j = i - 16384;
    Fh[j] = f2bf(fchW[j]);
  } else if (i < 16384 + 32768 + 131072) {
    int j = i - 49152;
    F2h[j] = f2bf(fc2W[j]);
  }
}

// ---------------- g = relu( (x@lin0^T+b) * sigmoid(x@sig0^T+b) ), bf16 out; also emits xh (bf16 x)
__global__ __launch_bounds__(256) void gemm_g(
    const float* __restrict__ x,
    const short* __restrict__ W1h, const short* __restrict__ W1l, const short* __restrict__ W2h,
    const float* __restrict__ lin0b, const float* __restrict__ sig0b,
    short* __restrict__ Gh, short* __restrict__ xh) {
  __shared__ short Ah[64 * 256];
  __shared__ short Al[64 * 256];
  int tid = threadIdx.x;
  int row0 = blockIdx.x * 64;
  #pragma unroll
  for (int i = 0; i < 16; ++i) {
    int f4 = tid + i * 256;
    int r = f4 >> 6;
    int k = (f4 & 63) << 2;
    f32x4 v = *reinterpret_cast<const f32x4*>(x + (size_t)(row0 + r) * KIN + k);
    s16x4 hh, ll;
    #pragma unroll
    for (int j = 0; j < 4; ++j) {
      short hb = f2bf(v[j]);
      hh[j] = hb;
      ll[j] = f2bf(v[j] - bf2f(hb));
    }
    int sidx = (r * 256 + k) ^ ((r & 7) << 3);
    *reinterpret_cast<s16x4*>(&Ah[sidx]) = hh;
    *reinterpret_cast<s16x4*>(&Al[sidx]) = ll;
    *reinterpret_cast<s16x4*>(xh + (size_t)(row0 + r) * KIN + k) = hh;
  }
  __syncthreads();
  int w = tid >> 6, l = tid & 63;
  int lr = l & 15, lg = l >> 4;
  int c = w * 16 + lr;
  f32x4 acc1[4], acc2[4];
  #pragma unroll
  for (int rt = 0; rt < 4; ++rt) { acc1[rt] = (f32x4)0.f; acc2[rt] = (f32x4)0.f; }
  #pragma unroll
  for (int ks = 0; ks < 8; ++ks) {
    int kk = ks * 32 + lg * 8;
    bf16x8 b2 = ldfrag(W2h + c * 256 + kk);
    #pragma unroll
    for (int rt = 0; rt < 4; ++rt) {
      int r = rt * 16 + lr;
      bf16x8 a = ldfrag(&Ah[(r * 256 + kk) ^ ((r & 7) << 3)]);
      acc2[rt] = mfma16(a, b2, acc2[rt]);
    }
  }
  #pragma unroll
  for (int ks = 0; ks < 8; ++ks) {
    int kk = ks * 32 + lg * 8;
    bf16x8 b1h = ldfrag(W1h + c * 256 + kk);
    bf16x8 b1l = ldfrag(W1l + c * 256 + kk);
    #pragma unroll
    for (int rt = 0; rt < 4; ++rt) {
      int r = rt * 16 + lr;
      int si = (r * 256 + kk) ^ ((r & 7) << 3);
      bf16x8 ah = ldfrag(&Ah[si]);
      bf16x8 al = ldfrag(&Al[si]);
      acc1[rt] = mfma16(ah, b1h, acc1[rt]);
      acc1[rt] = mfma16(ah, b1l, acc1[rt]);
      acc1[rt] = mfma16(al, b1h, acc1[rt]);
    }
  }
  float bl = lin0b[c], bs = sig0b[c];
  #pragma unroll
  for (int rt = 0; rt < 4; ++rt) {
    #pragma unroll
    for (int j = 0; j < 4; ++j) {
      int row = row0 + rt * 16 + lg * 4 + j;
      float y1 = acc1[rt][j] + bl;
      float y2 = acc2[rt][j] + bs;
      float g = y1 * fsigmoid(y2);
      g = g > 0.f ? g : 0.f;
      Gh[(size_t)row * HY + c] = f2bf(g);
    }
  }
}

// ---------------- gemm_b: m97-style 128x128 tile, BK=64, global_load_lds staging.
// K-steps 0-3: a2 += xh @ F2h^T ; step 4: aF += g @ Fh^T. Epilogue: (aF+bc)*sigmoid(a2+b2c).
// grid 2048 = 512 rowTiles x 4 colTiles, XCD-swizzled. 4 waves, wave = 64x64 quadrant.
__global__ __launch_bounds__(256) void gemm_b(
    const short* __restrict__ xh, const short* __restrict__ Gh,
    const short* __restrict__ F2h, const short* __restrict__ Fh,
    const float* __restrict__ fchb, const float* __restrict__ fc2b,
    float* __restrict__ bout) {
  __shared__ short Ab[2][128 * 64];
  __shared__ short Bb[2][128 * 64];
  int tid = threadIdx.x;
  int w = tid >> 6, l = tid & 63;
  int lr = l & 15, lg = l >> 4;
  int r0 = (w >> 1) * 64, c0 = (w & 1) * 64;
  int bid = blockIdx.x;
  int v = (bid & 7) * 256 + (bid >> 3);        // bijective XCD swizzle (2048 % 8 == 0)
  int rowTile = v & 511;
  int colTile = v >> 9;
  int row0 = rowTile * 128;
  int col0 = colTile * 128;

  // stage K-step t into buffer bufi. LDS linear dest; inverse-swizzled GLOBAL source (rule #21).
  auto stage = [&](int t, int bufi) {
    #pragma unroll
    for (int j = 0; j < 4; ++j) {
      int flat = (w * 4 + j) * 64 + l;         // 16B slot index in [0,1024)
      int row = flat >> 3, sp = flat & 7;      // 8 slots x 16B = 128B per row
      int seg = sp ^ (row & 7);                // inverse of read-side XOR
      const short* asrc = (t < 4) ? xh + (size_t)(row0 + row) * KIN + t * 64 + seg * 8
                                  : Gh + (size_t)(row0 + row) * HY + seg * 8;
      const short* bsrc = (t < 4) ? F2h + (size_t)(col0 + row) * KIN + t * 64 + seg * 8
                                  : Fh + (size_t)(col0 + row) * HY + seg * 8;
      __builtin_amdgcn_global_load_lds(GP(asrc), LP(&Ab[bufi][(w * 4 + j) * 512]), 16, 0, 0);
      __builtin_amdgcn_global_load_lds(GP(bsrc), LP(&Bb[bufi][(w * 4 + j) * 512]), 16, 0, 0);
    }
  };
  auto compute = [&](int bufi, f32x4 (&acc)[4][4]) {
    #pragma unroll
    for (int ksl = 0; ksl < 2; ++ksl) {
      bf16x8 Af[4], Bf[4];
      #pragma unroll
      for (int i = 0; i < 4; ++i) {
        int row = r0 + i * 16 + lr;
        Af[i] = ldfrag(&Ab[bufi][row * 64 + ((ksl * 32 + lg * 8) ^ ((row & 7) << 3))]);
        int col = c0 + i * 16 + lr;
        Bf[i] = ldfrag(&Bb[bufi][col * 64 + ((ksl * 32 + lg * 8) ^ ((col & 7) << 3))]);
      }
      #pragma unroll
      for (int rt = 0; rt < 4; ++rt)
        #pragma unroll
        for (int ct = 0; ct < 4; ++ct)
          acc[rt][ct] = mfma16(Af[rt], Bf[ct], acc[rt][ct]);
    }
  };

  f32x4 acc2[4][4], accF[4][4];
  #pragma unroll
  for (int rt = 0; rt < 4; ++rt)
    #pragma unroll
    for (int ct = 0; ct < 4; ++ct) { acc2[rt][ct] = (f32x4)0.f; accF[rt][ct] = (f32x4)0.f; }

  stage(0, 0);
  __syncthreads();                // drains vmcnt before first compute
  stage(1, 1); compute(0, acc2); __syncthreads();
  stage(2, 0); compute(1, acc2); __syncthreads();
  stage(3, 1); compute(0, acc2); __syncthreads();
  stage(4, 0); compute(1, acc2); __syncthreads();
  compute(0, accF);

  #pragma unroll
  for (int ct = 0; ct < 4; ++ct) {
    int col = col0 + c0 + ct * 16 + lr;
    float bc = fchb[col], b2c = fc2b[col];
    #pragma unroll
    for (int rt = 0; rt < 4; ++rt) {
      int rowb = row0 + r0 + rt * 16 + lg * 4;
      #pragma unroll
      for (int j = 0; j < 4; ++j) {
        float alpha = fsigmoid(acc2[rt][ct][j] + b2c);
        bout[(size_t)(rowb + j) * HOUT + col] = (accF[rt][ct][j] + bc) * alpha;
      }
    }
  }
}

// ---------------- scan pass A: per-chunk max-plus operator (C,S). 1 wave/wg, 8 ch/lane.
__global__ __launch_bounds__(64) void scan_passA(const float* __restrict__ bm,
                                                 float* __restrict__ Cc, float* __restrict__ Sc) {
  int bc = blockIdx.x;
  int batch = bc >> 7, chunk = bc & (NC - 1);
  int l = threadIdx.x;
  const float* bp = bm + ((size_t)batch * SEQ + chunk * LC) * HOUT + l * 8;
  f32x4 v0 = *reinterpret_cast<const f32x4*>(bp);
  f32x4 v1 = *reinterpret_cast<const f32x4*>(bp + 4);
  float C[8], S[8];
  #pragma unroll
  for (int i = 0; i < 4; ++i) { S[i] = v0[i]; S[4 + i] = v1[i]; C[i] = 0.f; C[4 + i] = 0.f; }
  for (int t = 1; t < LC; ++t) {
    const float* bt = bp + (size_t)t * HOUT;
    v0 = *reinterpret_cast<const f32x4*>(bt);
    v1 = *reinterpret_cast<const f32x4*>(bt + 4);
    float bb[8];
    #pragma unroll
    for (int i = 0; i < 4; ++i) { bb[i] = v0[i]; bb[4 + i] = v1[i]; }
    float pC = __shfl(C[7], (l + 63) & 63);
    float pS = __shfl(S[7], (l + 63) & 63);
    #pragma unroll
    for (int i = 7; i >= 1; --i) { C[i] = fmaxf(0.f, bb[i] + C[i - 1]); S[i] = bb[i] + S[i - 1]; }
    C[0] = fmaxf(0.f, bb[0] + pC);
    S[0] = bb[0] + pS;
  }
  float* cp = Cc + (size_t)bc * HOUT + l * 8;
  float* sp = Sc + (size_t)bc * HOUT + l * 8;
  #pragma unroll
  for (int i = 0; i < 8; ++i) { cp[i] = C[i]; sp[i] = S[i]; }
}

// ---------------- combine: sequential over chunks per batch; emits h_in per chunk + last.
__global__ __launch_bounds__(64) void scan_combine(const float* __restrict__ hidden,
                                                   const float* __restrict__ Cc, const float* __restrict__ Sc,
                                                   float* __restrict__ hIn, float* __restrict__ lastOut) {
  int batch = blockIdx.x;
  int l = threadIdx.x;
  float h[8];
  const float* hp = hidden + batch * HOUT + l * 8;
  #pragma unroll
  for (int i = 0; i < 8; ++i) h[i] = hp[i];
  size_t base0 = ((size_t)batch * NC) * HOUT + l * 8;
  f32x4 c0 = *reinterpret_cast<const f32x4*>(Cc + base0);
  f32x4 c1 = *reinterpret_cast<const f32x4*>(Cc + base0 + 4);
  f32x4 s0 = *reinterpret_cast<const f32x4*>(Sc + base0);
  f32x4 s1 = *reinterpret_cast<const f32x4*>(Sc + base0 + 4);
  for (int c = 0; c < NC; ++c) {
    size_t base = base0 + (size_t)c * HOUT;
    f32x4 nc0, nc1, ns0, ns1;
    if (c + 1 < NC) {
      size_t nb = base + HOUT;
      nc0 = *reinterpret_cast<const f32x4*>(Cc + nb);
      nc1 = *reinterpret_cast<const f32x4*>(Cc + nb + 4);
      ns0 = *reinterpret_cast<const f32x4*>(Sc + nb);
      ns1 = *reinterpret_cast<const f32x4*>(Sc + nb + 4);
    }
    #pragma unroll
    for (int i = 0; i < 8; ++i) hIn[base + i] = h[i];
    float hs[8];
    #pragma unroll
    for (int i = 0; i < 8; ++i) hs[i] = __shfl(h[i], (l + 64 - (LC / 8)) & 63);
    #pragma unroll
    for (int i = 0; i < 4; ++i) {
      h[i]     = fmaxf(c0[i], s0[i] + hs[i]);
      h[4 + i] = fmaxf(c1[i], s1[i] + hs[4 + i]);
    }
    c0 = nc0; c1 = nc1; s0 = ns0; s1 = ns1;
  }
  float* lp = lastOut + batch * HOUT + l * 8;
  #pragma unroll
  for (int i = 0; i < 8; ++i) lp[i] = h[i];
}

// ---------------- pass B: replay recurrence within chunk, overwrite b with h in place.
__global__ __launch_bounds__(64) void scan_passB(float* __restrict__ bm, const float* __restrict__ hIn) {
  int bc = blockIdx.x;
  int batch = bc >> 7, chunk = bc & (NC - 1);
  int l = threadIdx.x;
  const float* hp = hIn + (size_t)bc * HOUT + l * 8;
  float h[8];
  #pragma unroll
  for (int i = 0; i < 8; ++i) h[i] = hp[i];
  float* bp = bm + ((size_t)batch * SEQ + chunk * LC) * HOUT + l * 8;
  for (int t = 0; t < LC; ++t) {
    float* bt = bp + (size_t)t * HOUT;
    f32x4 v0 = *reinterpret_cast<const f32x4*>(bt);
    f32x4 v1 = *reinterpret_cast<const f32x4*>(bt + 4);
    float bb[8];
    #pragma unroll
    for (int i = 0; i < 4; ++i) { bb[i] = v0[i]; bb[4 + i] = v1[i]; }
    float ph = __shfl(h[7], (l + 63) & 63);
    #pragma unroll
    for (int i = 7; i >= 1; --i) h[i] = fmaxf(0.f, bb[i] + h[i - 1]);
    h[0] = fmaxf(0.f, bb[0] + ph);
    f32x4 o0, o1;
    #pragma unroll
    for (int i = 0; i < 4; ++i) { o0[i] = h[i]; o1[i] = h[4 + i]; }
    *reinterpret_cast<f32x4*>(bt) = o0;
    *reinterpret_cast<f32x4*>(bt + 4) = o1;
  }
}

extern "C" void kernel_launch(void* const* d_in, const int* in_sizes, int n_in,
                              void* d_out, int out_size, void* d_ws, size_t ws_size,
                              hipStream_t stream) {
  (void)in_sizes; (void)n_in; (void)out_size; (void)ws_size;
  const float* x      = (const float*)d_in[0];
  const float* hidden = (const float*)d_in[1];
  const float* lin0W  = (const float*)d_in[2];
  const float* lin0b  = (const float*)d_in[3];
  const float* sig0W  = (const float*)d_in[4];
  const float* sig0b  = (const float*)d_in[5];
  const float* fchW   = (const float*)d_in[6];
  const float* fchb   = (const float*)d_in[7];
  const float* fc2W   = (const float*)d_in[8];
  const float* fc2b   = (const float*)d_in[9];
  float* outO  = (float*)d_out;
  float* lastO = outO + (size_t)NROWS * HOUT;

  char* wsb = (char*)d_ws;
  size_t off = 0;
  auto alloc = [&](size_t bytes) { char* p = wsb + off; off += (bytes + 255) & ~(size_t)255; return p; };
  float* Cc  = (float*)alloc((size_t)NBATCH * NC * HOUT * 4);
  float* Sc  = (float*)alloc((size_t)NBATCH * NC * HOUT * 4);
  float* hIn = (float*)alloc((size_t)NBATCH * NC * HOUT * 4);
  short* W1h = (short*)alloc(HY * KIN * 2);
  short* W1l = (short*)alloc(HY * KIN * 2);
  short* W2h = (short*)alloc(HY * KIN * 2);
  short* Fh  = (short*)alloc(HOUT * HY * 2);
  short* F2h = (short*)alloc(HOUT * KIN * 2);
  short* Gh  = (short*)alloc((size_t)NROWS * HY * 2);
  short* xh  = (short*)alloc((size_t)NROWS * KIN * 2);

  prep_w<<<704, 256, 0, stream>>>(lin0W, sig0W, fchW, fc2W, W1h, W1l, W2h, Fh, F2h);
  gemm_g<<<NROWS / 64, 256, 0, stream>>>(x, W1h, W1l, W2h, lin0b, sig0b, Gh, xh);
  gemm_b<<<2048, 256, 0, stream>>>(xh, Gh, F2h, Fh, fchb, fc2b, outO);
  scan_passA<<<NBATCH * NC, 64, 0, stream>>>(outO, Cc, Sc);
  scan_combine<<<NBATCH, 64, 0, stream>>>(hidden, Cc, Sc, hIn, lastO);
  scan_passB<<<NBATCH * NC, 64, 0, stream>>>(outO, hIn);
}